// Round 5
// baseline (155.098 us; speedup 1.0000x reference)
//
#include <hip/hip_runtime.h>
#include <math.h>

#define NB 256        // batch = grid
#define N 128         // DIMX = DIMY = DIMH
#define NTHREADS 512  // 8 waves: thread = (k<<2)|h, k=0..127 row, h=0..3 K-quarter
#define MAX_IT 500
// LDS vectors: 4 slices of 32 floats, slice stride 40 -> slice h starts at
// bank 8h, so the 4 h-broadcast reads of a ds_read_b128 hit disjoint banks.
#define SLICE 40
#define SLOT(k) ((((k) >> 5) * SLICE) + ((k) & 31))
#define LDSVEC (3 * SLICE + 32)

// Nesterov (strongly convex): mu=0.5. R2 (alpha=1.25 converged on every
// sample) proves lambda_max < 1.6; use L=1.7 for margin. kappa=3.4.
#define NALPHA 0.5882353f            // 1/L
#define NBETA  0.2967437f            // (sqrt(k)-1)/(sqrt(k)+1)
// Per-coordinate exit tolerance: |r_k| <= 2.5e-4 for all k
//   => ||r||_2 <= 2.83e-3 => ||y1-y1*||_2 <= 5.7e-3 (mu=0.5)
//   => |mean_k err| <= 5e-4, far under the 1.79e-2 output threshold.
#define TPC 2.5e-4f

// Quad reduction via DPP quad_perm adds (lanes 4q..4q+3 hold the 4 h's of one
// k). 0xB1 = quad_perm[1,0,3,2] (xor1), 0x4E = quad_perm[2,3,0,1] (xor2).
// ~8 cyc vs ~70 for the ds_swizzle-routed __shfl_xor pair.
template <int CTRL>
__device__ __forceinline__ float dpp_addx(float v) {
    int sw = __builtin_amdgcn_update_dpp(0, __float_as_int(v), CTRL, 0xF, 0xF, true);
    return v + __int_as_float(sw);
}
__device__ __forceinline__ float quad_sum(float p) {
    p = dpp_addx<0xB1>(p);
    p = dpp_addx<0x4E>(p);
    return p;
}
__device__ __forceinline__ float wave_sum(float p) {  // epilogue only
    p += __shfl_xor(p, 1);
    p += __shfl_xor(p, 2);
    p += __shfl_xor(p, 4);
    p += __shfl_xor(p, 8);
    p += __shfl_xor(p, 16);
    p += __shfl_xor(p, 32);
    return p;
}
__device__ __forceinline__ float softplus_f(float s) {
    float e = __expf(-fabsf(s));
    return fmaxf(s, 0.f) + __logf(1.f + e);
}
__device__ __forceinline__ float sigmoid_f(float s) {
    float e = __expf(-fabsf(s));
    float r = 1.f / (1.f + e);
    return s >= 0.f ? r : 1.f - r;
}

__device__ __forceinline__ float mv_row(const float* __restrict__ W,
                                        const float* __restrict__ V,
                                        int k, int h) {
    const float4* wr = (const float4*)(W + k * N + h * 32);
    const float4* vr = (const float4*)(V + h * SLICE);
    float q0 = 0.f, q1 = 0.f, q2 = 0.f, q3 = 0.f;
#pragma unroll
    for (int i = 0; i < 8; ++i) {
        float4 w = wr[i], v = vr[i];
        q0 = fmaf(w.x, v.x, q0); q1 = fmaf(w.y, v.y, q1);
        q2 = fmaf(w.z, v.z, q2); q3 = fmaf(w.w, v.w, q3);
    }
    return quad_sum((q0 + q1) + (q2 + q3));
}

__global__ __launch_bounds__(NTHREADS, 2)
void picnn_solve(const float* __restrict__ x, const float* __restrict__ y,
                 const float* __restrict__ wuu0_w, const float* __restrict__ wuu0_b,
                 const float* __restrict__ wyu0_w, const float* __restrict__ wyu0_b,
                 const float* __restrict__ wy0,
                 const float* __restrict__ wu0_w, const float* __restrict__ wu0_b,
                 const float* __restrict__ wuu1_w, const float* __restrict__ wuu1_b,
                 const float* __restrict__ wzu1_w, const float* __restrict__ wzu1_b,
                 const float* __restrict__ wz1,
                 const float* __restrict__ wyu1_w, const float* __restrict__ wyu1_b,
                 const float* __restrict__ wy1,
                 const float* __restrict__ wu1_w, const float* __restrict__ wu1_b,
                 const float* __restrict__ wzu2_w, const float* __restrict__ wzu2_b,
                 const float* __restrict__ wz2,
                 const float* __restrict__ wyu2_w, const float* __restrict__ wyu2_b,
                 const float* __restrict__ wy2,
                 float* __restrict__ out)
{
    const int b = blockIdx.x;
    const int t = threadIdx.x;
    const int k = t >> 2;   // output row 0..127
    const int h = t & 3;    // K-quarter 0..3
    const int wave = t >> 6;
    const int lane = t & 63;

    __shared__ __align__(16) float xv[LDSVEC];
    __shared__ __align__(16) float u0v[LDSVEC];
    __shared__ __align__(16) float u1v[LDSVEC];
    __shared__ __align__(16) float t0s[LDSVEC];
    __shared__ __align__(16) float t2s[LDSVEC];
    __shared__ __align__(16) float t1s[LDSVEC];
    __shared__ __align__(16) float d2s[LDSVEC];
    __shared__ __align__(16) float d1s[LDSVEC];
    __shared__ float rp[8];
    __shared__ int cflag[2];   // ping-pong any-lane-unconverged flags

    if (t < N) xv[SLOT(t)] = x[b * N + t];
    if (t < 2) cflag[t] = 0;
    __syncthreads();

    // ---- per-sample iteration-invariant precompute ----
    float u0k = softplus_f(mv_row(wuu0_w, xv, k, h) + wuu0_b[k]);
    float a0  = mv_row(wyu0_w, xv, k, h) + wyu0_b[k];
    float c0  = mv_row(wu0_w,  xv, k, h) + wu0_b[k];
    if (h == 0) u0v[SLOT(k)] = u0k;
    __syncthreads();

    float u1k = softplus_f(mv_row(wuu1_w, u0v, k, h) + wuu1_b[k]);
    float zu  = softplus_f(mv_row(wzu1_w, u0v, k, h) + wzu1_b[k]);
    float a1  = mv_row(wyu1_w, u0v, k, h) + wyu1_b[k];
    float c1  = mv_row(wu1_w,  u0v, k, h) + wu1_b[k];
    if (h == 0) u1v[SLOT(k)] = u1k;
    __syncthreads();

    float a2 = mv_row(wyu2_w, u1v, k, h) + wyu2_b[k];
    float e2 = a2 * wy2[k];
    float dp;
    {
        const float4* wr = (const float4*)(wzu2_w + h * 32);
        const float4* vr = (const float4*)(u1v + h * SLICE);
        float q0 = 0.f, q1 = 0.f, q2 = 0.f, q3 = 0.f;
#pragma unroll
        for (int i = 0; i < 8; ++i) {
            float4 w = wr[i], v = vr[i];
            q0 = fmaf(w.x, v.x, q0); q1 = fmaf(w.y, v.y, q1);
            q2 = fmaf(w.z, v.z, q2); q3 = fmaf(w.w, v.w, q3);
        }
        float zu2 = softplus_f(quad_sum((q0 + q1) + (q2 + q3)) + wzu2_b[0]);
        dp = zu2 * fmaxf(wz2[k], 0.f);
    }

    // ---- register-resident weights AFTER precompute (hoisting earlier
    // causes VGPR spill -- R3's 8.7 MB scratch WRITE_SIZE) ----
    float4 wf0[8], wf1[8], wf2[8];  // wy0 / clip(wz1) / wy1, row k, quarter h
    float4 wb0[8], wb1[8], wb2[8];  // same matrices, column k, row-quarter h
    {
        const float4* r0 = (const float4*)(wy0 + k * N + h * 32);
        const float4* r1 = (const float4*)(wz1 + k * N + h * 32);
        const float4* r2 = (const float4*)(wy1 + k * N + h * 32);
#pragma unroll
        for (int i = 0; i < 8; ++i) {
            wf0[i] = r0[i];
            float4 z = r1[i];
            z.x = fmaxf(z.x, 0.f); z.y = fmaxf(z.y, 0.f);
            z.z = fmaxf(z.z, 0.f); z.w = fmaxf(z.w, 0.f);
            wf1[i] = z;
            wf2[i] = r2[i];
        }
#pragma unroll
        for (int i = 0; i < 8; ++i) {
            int r = h * 32 + 4 * i;
            wb0[i].x = wy0[(r + 0) * N + k]; wb0[i].y = wy0[(r + 1) * N + k];
            wb0[i].z = wy0[(r + 2) * N + k]; wb0[i].w = wy0[(r + 3) * N + k];
            wb1[i].x = fmaxf(wz1[(r + 0) * N + k], 0.f);
            wb1[i].y = fmaxf(wz1[(r + 1) * N + k], 0.f);
            wb1[i].z = fmaxf(wz1[(r + 2) * N + k], 0.f);
            wb1[i].w = fmaxf(wz1[(r + 3) * N + k], 0.f);
            wb2[i].x = wy1[(r + 0) * N + k]; wb2[i].y = wy1[(r + 1) * N + k];
            wb2[i].z = wy1[(r + 2) * N + k]; wb2[i].w = wy1[(r + 3) * N + k];
        }
    }

    const float yk = y[b * N + k];
    // init zeroing the linear residual part: g ~ 0.5*y1 + e2 -> y1_0 = 2(y-e2)
    float y1v = 2.f * (yk - e2);   // current iterate y1_t
    float vv  = y1v;               // Nesterov extrapolated point v_t
    if (h == 0) { t0s[SLOT(k)] = vv * a0; t2s[SLOT(k)] = vv * a1; }
    __syncthreads();

    for (int it = 1; it <= MAX_IT; ++it) {
        // S1: s1 = t0@wy0^T + c0 ; s2a = t2@wy1^T  (fused pass over t0,t2)
        const float4* t0r = (const float4*)(t0s + h * SLICE);
        const float4* t2r = (const float4*)(t2s + h * SLICE);
        float p0 = 0.f, p1 = 0.f, p2 = 0.f, p3 = 0.f;
        float q0 = 0.f, q1 = 0.f, q2 = 0.f, q3 = 0.f;
#pragma unroll
        for (int i = 0; i < 8; ++i) {
            float4 v0 = t0r[i], v2 = t2r[i];
            p0 = fmaf(wf0[i].x, v0.x, p0); p1 = fmaf(wf0[i].y, v0.y, p1);
            p2 = fmaf(wf0[i].z, v0.z, p2); p3 = fmaf(wf0[i].w, v0.w, p3);
            q0 = fmaf(wf2[i].x, v2.x, q0); q1 = fmaf(wf2[i].y, v2.y, q1);
            q2 = fmaf(wf2[i].z, v2.z, q2); q3 = fmaf(wf2[i].w, v2.w, q3);
        }
        float s1  = quad_sum((p0 + p1) + (p2 + p3)) + c0;
        float s2a = quad_sum((q0 + q1) + (q2 + q3));
        float e1 = __expf(-fabsf(s1));
        float z1 = fmaxf(s1, 0.f) + __logf(1.f + e1);
        float rr1 = 1.f / (1.f + e1);
        float sig1 = (s1 >= 0.f) ? rr1 : 1.f - rr1;
        if (h == 0) t1s[SLOT(k)] = z1 * zu;
        __syncthreads();

        // S2: s2 = t1@wz1c^T + s2a + c1 ; d2 = dp*sigma(s2)
        const float4* t1r = (const float4*)(t1s + h * SLICE);
        p0 = p1 = p2 = p3 = 0.f;
#pragma unroll
        for (int i = 0; i < 8; ++i) {
            float4 v1 = t1r[i];
            p0 = fmaf(wf1[i].x, v1.x, p0); p1 = fmaf(wf1[i].y, v1.y, p1);
            p2 = fmaf(wf1[i].z, v1.z, p2); p3 = fmaf(wf1[i].w, v1.w, p3);
        }
        float s2 = quad_sum((p0 + p1) + (p2 + p3)) + s2a + c1;
        float d2 = dp * sigmoid_f(s2);
        if (h == 0) d2s[SLOT(k)] = d2;
        __syncthreads();

        // S3: q = d2@wz1c (cols) ; gc = d2@wy1 (cols) ; d1 = q*zu*sig1
        // (also: reset the OTHER exit flag here -- two barriers separate this
        //  write from both its previous read and its next set)
        if (t == 0) cflag[(it + 1) & 1] = 0;
        const float4* d2r = (const float4*)(d2s + h * SLICE);
        p0 = p1 = p2 = p3 = 0.f; q0 = q1 = q2 = q3 = 0.f;
#pragma unroll
        for (int i = 0; i < 8; ++i) {
            float4 d = d2r[i];
            p0 = fmaf(wb1[i].x, d.x, p0); p1 = fmaf(wb1[i].y, d.y, p1);
            p2 = fmaf(wb1[i].z, d.z, p2); p3 = fmaf(wb1[i].w, d.w, p3);
            q0 = fmaf(wb2[i].x, d.x, q0); q1 = fmaf(wb2[i].y, d.y, q1);
            q2 = fmaf(wb2[i].z, d.z, q2); q3 = fmaf(wb2[i].w, d.w, q3);
        }
        float qv = quad_sum((p0 + p1) + (p2 + p3));
        float gc = quad_sum((q0 + q1) + (q2 + q3));
        float d1 = qv * zu * sig1;
        if (h == 0) d1s[SLOT(k)] = d1;
        __syncthreads();

        // S4: gb = d1@wy0 (cols); g(v); Nesterov update; cheap exit flag
        const float4* d1r = (const float4*)(d1s + h * SLICE);
        p0 = p1 = p2 = p3 = 0.f;
#pragma unroll
        for (int i = 0; i < 8; ++i) {
            float4 d = d1r[i];
            p0 = fmaf(wb0[i].x, d.x, p0); p1 = fmaf(wb0[i].y, d.y, p1);
            p2 = fmaf(wb0[i].z, d.z, p2); p3 = fmaf(wb0[i].w, d.w, p3);
        }
        float gb = quad_sum((p0 + p1) + (p2 + p3));
        float g = fmaf(0.5f, vv, e2) + gc * a1 + gb * a0;
        float rres = yk - g;                  // -grad F at v
        float y1n = fmaf(NALPHA, rres, vv);   // y1_{t+1} = v - a*gradF(v)
        vv = fmaf(NBETA, y1n - y1v, y1n);     // v_{t+1} = y1_{t+1} + b*(...)
        y1v = y1n;
        if (h == 0) { t0s[SLOT(k)] = vv * a0; t2s[SLOT(k)] = vv * a1; }
        if (__ballot(fabsf(rres) > TPC)) {    // any lane in wave unconverged
            if (lane == 0) cflag[it & 1] = 1;
        }
        __syncthreads();
        if (!cflag[it & 1]) break;            // uniform: flag read post-barrier
    }

    // out[b] = mean_k(y1 + y)
    float v = wave_sum(y1v + yk);           // 4x duplicated per k
    if (lane == 0) rp[wave] = v;
    __syncthreads();
    if (t == 0) {
        float s = ((rp[0] + rp[1]) + (rp[2] + rp[3]))
                + ((rp[4] + rp[5]) + (rp[6] + rp[7]));
        out[b] = s * (1.f / 512.f);         // /4 duplication /128 mean
    }
}

extern "C" void kernel_launch(void* const* d_in, const int* in_sizes, int n_in,
                              void* d_out, int out_size, void* d_ws, size_t ws_size,
                              hipStream_t stream) {
    const float* x      = (const float*)d_in[0];
    const float* y      = (const float*)d_in[1];
    const float* wuu0_w = (const float*)d_in[2];
    const float* wuu0_b = (const float*)d_in[3];
    const float* wyu0_w = (const float*)d_in[4];
    const float* wyu0_b = (const float*)d_in[5];
    const float* wy0    = (const float*)d_in[6];
    const float* wu0_w  = (const float*)d_in[7];
    const float* wu0_b  = (const float*)d_in[8];
    const float* wuu1_w = (const float*)d_in[9];
    const float* wuu1_b = (const float*)d_in[10];
    const float* wzu1_w = (const float*)d_in[11];
    const float* wzu1_b = (const float*)d_in[12];
    const float* wz1    = (const float*)d_in[13];
    const float* wyu1_w = (const float*)d_in[14];
    const float* wyu1_b = (const float*)d_in[15];
    const float* wy1    = (const float*)d_in[16];
    const float* wu1_w  = (const float*)d_in[17];
    const float* wu1_b  = (const float*)d_in[18];
    const float* wzu2_w = (const float*)d_in[19];
    const float* wzu2_b = (const float*)d_in[20];
    const float* wz2    = (const float*)d_in[21];
    const float* wyu2_w = (const float*)d_in[22];
    const float* wyu2_b = (const float*)d_in[23];
    const float* wy2    = (const float*)d_in[24];
    // d_in[25]/[26] (wu2_w, wu2_b) shift the value, not the gradient -> unused
    float* out = (float*)d_out;

    picnn_solve<<<dim3(NB), dim3(NTHREADS), 0, stream>>>(
        x, y, wuu0_w, wuu0_b, wyu0_w, wyu0_b, wy0, wu0_w, wu0_b,
        wuu1_w, wuu1_b, wzu1_w, wzu1_b, wz1, wyu1_w, wyu1_b, wy1, wu1_w, wu1_b,
        wzu2_w, wzu2_b, wz2, wyu2_w, wyu2_b, wy2, out);
}

// Round 6
// 152.548 us; speedup vs baseline: 1.0167x; 1.0167x over previous
//
#include <hip/hip_runtime.h>
#include <math.h>

#define NB 256        // batch = grid
#define N 128         // DIMX = DIMY = DIMH
#define NTHREADS 512  // 8 waves: thread = (k<<2)|h, k=0..127 row, h=0..3 K-quarter
#define MAX_IT 500
// LDS vectors: 4 slices of 32 floats, slice stride 40 -> slice h starts at
// bank 8h, so the 4 h-broadcast reads of a ds_read_b128 hit disjoint banks.
#define SLICE 40
#define SLOT(k) ((((k) >> 5) * SLICE) + ((k) & 31))
#define LDSVEC (3 * SLICE + 32)
#define TP 132        // transpose staging pitch (words), multiple of 4 for b128

// Heavy-ball on spectrum [mu=0.5, L=1.45] (R2: alpha=1.25 GD converged fast ->
// lambda_max ~1.3-1.4; bulk at mu). alpha=4/(sqrt(L)+sqrt(mu))^2, beta=
// ((sqrt(L)-sqrt(mu))/(sqrt(L)+sqrt(mu)))^2 -> uniform |root| ~ 0.26/iter.
#define HBALPHA 1.10f
#define HBBETA  0.068f
// Per-coordinate exit: |r_k| <= 2.5e-4 for all k => ||r||2 <= 2.83e-3 =>
// ||y1-y1*|| <= 5.7e-3 (mu=0.5) => output mean err <= 5e-4 << 1.79e-2 thresh.
#define TPC 2.5e-4f

// Quad reduction via DPP quad_perm adds (lanes 4q..4q+3 hold the 4 h's of one
// k). 0xB1 = quad_perm[1,0,3,2] (xor1), 0x4E = quad_perm[2,3,0,1] (xor2).
template <int CTRL>
__device__ __forceinline__ float dpp_addx(float v) {
    int sw = __builtin_amdgcn_update_dpp(0, __float_as_int(v), CTRL, 0xF, 0xF, true);
    return v + __int_as_float(sw);
}
__device__ __forceinline__ float quad_sum(float p) {
    p = dpp_addx<0xB1>(p);
    p = dpp_addx<0x4E>(p);
    return p;
}
__device__ __forceinline__ float wave_sum(float p) {  // epilogue only
    p += __shfl_xor(p, 1);
    p += __shfl_xor(p, 2);
    p += __shfl_xor(p, 4);
    p += __shfl_xor(p, 8);
    p += __shfl_xor(p, 16);
    p += __shfl_xor(p, 32);
    return p;
}
__device__ __forceinline__ float softplus_f(float s) {
    float e = __expf(-fabsf(s));
    return fmaxf(s, 0.f) + __logf(1.f + e);
}
__device__ __forceinline__ float sigmoid_f(float s) {
    float e = __expf(-fabsf(s));
    float r = 1.f / (1.f + e);
    return s >= 0.f ? r : 1.f - r;
}

__device__ __forceinline__ float mv_row(const float* __restrict__ W,
                                        const float* __restrict__ V,
                                        int k, int h) {
    const float4* wr = (const float4*)(W + k * N + h * 32);
    const float4* vr = (const float4*)(V + h * SLICE);
    float q0 = 0.f, q1 = 0.f, q2 = 0.f, q3 = 0.f;
#pragma unroll
    for (int i = 0; i < 8; ++i) {
        float4 w = wr[i], v = vr[i];
        q0 = fmaf(w.x, v.x, q0); q1 = fmaf(w.y, v.y, q1);
        q2 = fmaf(w.z, v.z, q2); q3 = fmaf(w.w, v.w, q3);
    }
    return quad_sum((q0 + q1) + (q2 + q3));
}

__global__ __launch_bounds__(NTHREADS, 2)
void picnn_solve(const float* __restrict__ x, const float* __restrict__ y,
                 const float* __restrict__ wuu0_w, const float* __restrict__ wuu0_b,
                 const float* __restrict__ wyu0_w, const float* __restrict__ wyu0_b,
                 const float* __restrict__ wy0,
                 const float* __restrict__ wu0_w, const float* __restrict__ wu0_b,
                 const float* __restrict__ wuu1_w, const float* __restrict__ wuu1_b,
                 const float* __restrict__ wzu1_w, const float* __restrict__ wzu1_b,
                 const float* __restrict__ wz1,
                 const float* __restrict__ wyu1_w, const float* __restrict__ wyu1_b,
                 const float* __restrict__ wy1,
                 const float* __restrict__ wu1_w, const float* __restrict__ wu1_b,
                 const float* __restrict__ wzu2_w, const float* __restrict__ wzu2_b,
                 const float* __restrict__ wz2,
                 const float* __restrict__ wyu2_w, const float* __restrict__ wyu2_b,
                 const float* __restrict__ wy2,
                 float* __restrict__ out)
{
    const int b = blockIdx.x;
    const int t = threadIdx.x;
    const int k = t >> 2;   // output row 0..127
    const int h = t & 3;    // K-quarter 0..3
    const int wave = t >> 6;
    const int lane = t & 63;

    __shared__ __align__(16) float tb[N * TP];   // 67.6 KB transpose staging
    __shared__ __align__(16) float xv[LDSVEC];
    __shared__ __align__(16) float u0v[LDSVEC];
    __shared__ __align__(16) float u1v[LDSVEC];
    __shared__ __align__(16) float a0s[LDSVEC];
    __shared__ __align__(16) float a1s[LDSVEC];
    __shared__ __align__(16) float vs[LDSVEC];   // current iterate y1
    __shared__ __align__(16) float t1s[LDSVEC];
    __shared__ __align__(16) float d2s[LDSVEC];
    __shared__ __align__(16) float d1s[LDSVEC];
    __shared__ float rp[8];
    __shared__ int cflag[2];   // ping-pong any-lane-unconverged flags

    if (t < N) xv[SLOT(t)] = x[b * N + t];
    if (t < 2) cflag[t] = 0;
    __syncthreads();

    // ---- per-sample iteration-invariant precompute ----
    float u0k = softplus_f(mv_row(wuu0_w, xv, k, h) + wuu0_b[k]);
    float a0  = mv_row(wyu0_w, xv, k, h) + wyu0_b[k];
    float c0  = mv_row(wu0_w,  xv, k, h) + wu0_b[k];
    if (h == 0) { u0v[SLOT(k)] = u0k; a0s[SLOT(k)] = a0; }
    __syncthreads();

    float u1k = softplus_f(mv_row(wuu1_w, u0v, k, h) + wuu1_b[k]);
    float zu  = softplus_f(mv_row(wzu1_w, u0v, k, h) + wzu1_b[k]);
    float a1  = mv_row(wyu1_w, u0v, k, h) + wyu1_b[k];
    float c1  = mv_row(wu1_w,  u0v, k, h) + wu1_b[k];
    if (h == 0) { u1v[SLOT(k)] = u1k; a1s[SLOT(k)] = a1; }
    __syncthreads();

    float a2 = mv_row(wyu2_w, u1v, k, h) + wyu2_b[k];
    float e2 = a2 * wy2[k];
    float dp;
    {
        const float4* wr = (const float4*)(wzu2_w + h * 32);
        const float4* vr = (const float4*)(u1v + h * SLICE);
        float q0 = 0.f, q1 = 0.f, q2 = 0.f, q3 = 0.f;
#pragma unroll
        for (int i = 0; i < 8; ++i) {
            float4 w = wr[i], v = vr[i];
            q0 = fmaf(w.x, v.x, q0); q1 = fmaf(w.y, v.y, q1);
            q2 = fmaf(w.z, v.z, q2); q3 = fmaf(w.w, v.w, q3);
        }
        float zu2 = softplus_f(quad_sum((q0 + q1) + (q2 + q3)) + wzu2_b[0]);
        dp = zu2 * fmaxf(wz2[k], 0.f);
    }

    // ---- register-resident matrices with diag folding ----
    //   A0 = wy0 * diag(a0)   (rows: *a0_j ; cols: *a0_k)
    //   Wz = clip(wz1)
    //   B  = wy1 * diag(a1)
    // Rows from coalesced global loads; columns via LDS transpose (tb),
    // replacing R5's 96 strided global gathers. (Loaded AFTER precompute:
    // hoisting earlier spills VGPRs -- R3's 8.7 MB scratch.)
    float4 wf0[8], wf1[8], wf2[8];  // rows, quarter h
    float4 wb0[8], wb1[8], wb2[8];  // columns, row-quarter h
    const int rowbase = k * TP + h * 32;

    {   // A0 from wy0
        const float4* r0 = (const float4*)(wy0 + k * N + h * 32);
        const float4* as = (const float4*)(a0s + h * SLICE);
        float4* tw = (float4*)(tb + rowbase);
#pragma unroll
        for (int i = 0; i < 8; ++i) {
            float4 w = r0[i], s = as[i];
            tw[i] = w;                               // stage RAW row
            w.x *= s.x; w.y *= s.y; w.z *= s.z; w.w *= s.w;
            wf0[i] = w;                              // A0 row
        }
        __syncthreads();
#pragma unroll
        for (int i = 0; i < 8; ++i) {
            int r = (h * 32 + 4 * i) * TP + k;
            wb0[i].x = tb[r] * a0; wb0[i].y = tb[r + TP] * a0;
            wb0[i].z = tb[r + 2 * TP] * a0; wb0[i].w = tb[r + 3 * TP] * a0;
        }
        __syncthreads();
    }
    {   // Wz from clip(wz1)
        const float4* r1 = (const float4*)(wz1 + k * N + h * 32);
        float4* tw = (float4*)(tb + rowbase);
#pragma unroll
        for (int i = 0; i < 8; ++i) {
            float4 z = r1[i];
            z.x = fmaxf(z.x, 0.f); z.y = fmaxf(z.y, 0.f);
            z.z = fmaxf(z.z, 0.f); z.w = fmaxf(z.w, 0.f);
            wf1[i] = z;
            tw[i] = z;                               // stage CLIPPED row
        }
        __syncthreads();
#pragma unroll
        for (int i = 0; i < 8; ++i) {
            int r = (h * 32 + 4 * i) * TP + k;
            wb1[i].x = tb[r]; wb1[i].y = tb[r + TP];
            wb1[i].z = tb[r + 2 * TP]; wb1[i].w = tb[r + 3 * TP];
        }
        __syncthreads();
    }
    {   // B from wy1
        const float4* r2 = (const float4*)(wy1 + k * N + h * 32);
        const float4* as = (const float4*)(a1s + h * SLICE);
        float4* tw = (float4*)(tb + rowbase);
#pragma unroll
        for (int i = 0; i < 8; ++i) {
            float4 w = r2[i], s = as[i];
            tw[i] = w;                               // stage RAW row
            w.x *= s.x; w.y *= s.y; w.z *= s.z; w.w *= s.w;
            wf2[i] = w;                              // B row
        }
        __syncthreads();
#pragma unroll
        for (int i = 0; i < 8; ++i) {
            int r = (h * 32 + 4 * i) * TP + k;
            wb2[i].x = tb[r] * a1; wb2[i].y = tb[r + TP] * a1;
            wb2[i].z = tb[r + 2 * TP] * a1; wb2[i].w = tb[r + 3 * TP] * a1;
        }
        __syncthreads();
    }

    const float yk = y[b * N + k];
    // init zeroing the linear residual part: g ~ 0.5*y1 + e2 -> y1_0 = 2(y-e2)
    float y1v = 2.f * (yk - e2);
    float y1p = y1v;               // previous iterate (heavy-ball)
    if (h == 0) vs[SLOT(k)] = y1v;
    __syncthreads();

    for (int it = 1; it <= MAX_IT; ++it) {
        // S1: one vector read; s1 = A0rows.v + c0 ; s2a = Brows.v
        const float4* vr = (const float4*)(vs + h * SLICE);
        float p0 = 0.f, p1 = 0.f, p2 = 0.f, p3 = 0.f;
        float q0 = 0.f, q1 = 0.f, q2 = 0.f, q3 = 0.f;
#pragma unroll
        for (int i = 0; i < 8; ++i) {
            float4 v = vr[i];
            p0 = fmaf(wf0[i].x, v.x, p0); p1 = fmaf(wf0[i].y, v.y, p1);
            p2 = fmaf(wf0[i].z, v.z, p2); p3 = fmaf(wf0[i].w, v.w, p3);
            q0 = fmaf(wf2[i].x, v.x, q0); q1 = fmaf(wf2[i].y, v.y, q1);
            q2 = fmaf(wf2[i].z, v.z, q2); q3 = fmaf(wf2[i].w, v.w, q3);
        }
        float s1  = quad_sum((p0 + p1) + (p2 + p3)) + c0;
        float s2a = quad_sum((q0 + q1) + (q2 + q3));
        float e1 = __expf(-fabsf(s1));
        float z1 = fmaxf(s1, 0.f) + __logf(1.f + e1);
        float rr1 = 1.f / (1.f + e1);
        float sig1 = (s1 >= 0.f) ? rr1 : 1.f - rr1;
        if (h == 0) t1s[SLOT(k)] = z1 * zu;
        __syncthreads();

        // S2: s2 = Wzrows.t1 + s2a + c1 ; d2 = dp*sigma(s2)
        const float4* t1r = (const float4*)(t1s + h * SLICE);
        p0 = p1 = p2 = p3 = 0.f;
#pragma unroll
        for (int i = 0; i < 8; ++i) {
            float4 v1 = t1r[i];
            p0 = fmaf(wf1[i].x, v1.x, p0); p1 = fmaf(wf1[i].y, v1.y, p1);
            p2 = fmaf(wf1[i].z, v1.z, p2); p3 = fmaf(wf1[i].w, v1.w, p3);
        }
        float s2 = quad_sum((p0 + p1) + (p2 + p3)) + s2a + c1;
        float d2 = dp * sigmoid_f(s2);
        if (h == 0) d2s[SLOT(k)] = d2;
        __syncthreads();

        // S3: w = Wzcols.d2 ; gcB = Bcols.d2 ; d1 = w*zu*sig1
        // (reset the OTHER exit flag: >=1 barrier from its read & next set)
        if (t == 0) cflag[(it + 1) & 1] = 0;
        const float4* d2r = (const float4*)(d2s + h * SLICE);
        p0 = p1 = p2 = p3 = 0.f; q0 = q1 = q2 = q3 = 0.f;
#pragma unroll
        for (int i = 0; i < 8; ++i) {
            float4 d = d2r[i];
            p0 = fmaf(wb1[i].x, d.x, p0); p1 = fmaf(wb1[i].y, d.y, p1);
            p2 = fmaf(wb1[i].z, d.z, p2); p3 = fmaf(wb1[i].w, d.w, p3);
            q0 = fmaf(wb2[i].x, d.x, q0); q1 = fmaf(wb2[i].y, d.y, q1);
            q2 = fmaf(wb2[i].z, d.z, q2); q3 = fmaf(wb2[i].w, d.w, q3);
        }
        float wv  = quad_sum((p0 + p1) + (p2 + p3));
        float gcB = quad_sum((q0 + q1) + (q2 + q3));
        float d1 = wv * zu * sig1;
        if (h == 0) d1s[SLOT(k)] = d1;
        __syncthreads();

        // S4: gbA = A0cols.d1 ; g ; heavy-ball update; exit flag
        const float4* d1r = (const float4*)(d1s + h * SLICE);
        p0 = p1 = p2 = p3 = 0.f;
#pragma unroll
        for (int i = 0; i < 8; ++i) {
            float4 d = d1r[i];
            p0 = fmaf(wb0[i].x, d.x, p0); p1 = fmaf(wb0[i].y, d.y, p1);
            p2 = fmaf(wb0[i].z, d.z, p2); p3 = fmaf(wb0[i].w, d.w, p3);
        }
        float gbA = quad_sum((p0 + p1) + (p2 + p3));
        float g = fmaf(0.5f, y1v, e2) + gcB + gbA;
        float rres = yk - g;                        // -grad F at y1_t
        float y1n = y1v + HBALPHA * rres + HBBETA * (y1v - y1p);
        y1p = y1v; y1v = y1n;
        if (h == 0) vs[SLOT(k)] = y1v;
        if (__ballot(fabsf(rres) > TPC)) {          // any lane unconverged
            if (lane == 0) cflag[it & 1] = 1;
        }
        __syncthreads();
        if (!cflag[it & 1]) break;                  // uniform post-barrier read
    }

    // out[b] = mean_k(y1 + y)
    float v = wave_sum(y1v + yk);           // 4x duplicated per k
    if (lane == 0) rp[wave] = v;
    __syncthreads();
    if (t == 0) {
        float s = ((rp[0] + rp[1]) + (rp[2] + rp[3]))
                + ((rp[4] + rp[5]) + (rp[6] + rp[7]));
        out[b] = s * (1.f / 512.f);         // /4 duplication /128 mean
    }
}

extern "C" void kernel_launch(void* const* d_in, const int* in_sizes, int n_in,
                              void* d_out, int out_size, void* d_ws, size_t ws_size,
                              hipStream_t stream) {
    const float* x      = (const float*)d_in[0];
    const float* y      = (const float*)d_in[1];
    const float* wuu0_w = (const float*)d_in[2];
    const float* wuu0_b = (const float*)d_in[3];
    const float* wyu0_w = (const float*)d_in[4];
    const float* wyu0_b = (const float*)d_in[5];
    const float* wy0    = (const float*)d_in[6];
    const float* wu0_w  = (const float*)d_in[7];
    const float* wu0_b  = (const float*)d_in[8];
    const float* wuu1_w = (const float*)d_in[9];
    const float* wuu1_b = (const float*)d_in[10];
    const float* wzu1_w = (const float*)d_in[11];
    const float* wzu1_b = (const float*)d_in[12];
    const float* wz1    = (const float*)d_in[13];
    const float* wyu1_w = (const float*)d_in[14];
    const float* wyu1_b = (const float*)d_in[15];
    const float* wy1    = (const float*)d_in[16];
    const float* wu1_w  = (const float*)d_in[17];
    const float* wu1_b  = (const float*)d_in[18];
    const float* wzu2_w = (const float*)d_in[19];
    const float* wzu2_b = (const float*)d_in[20];
    const float* wz2    = (const float*)d_in[21];
    const float* wyu2_w = (const float*)d_in[22];
    const float* wyu2_b = (const float*)d_in[23];
    const float* wy2    = (const float*)d_in[24];
    // d_in[25]/[26] (wu2_w, wu2_b) shift the value, not the gradient -> unused
    float* out = (float*)d_out;

    picnn_solve<<<dim3(NB), dim3(NTHREADS), 0, stream>>>(
        x, y, wuu0_w, wuu0_b, wyu0_w, wyu0_b, wy0, wu0_w, wu0_b,
        wuu1_w, wuu1_b, wzu1_w, wzu1_b, wz1, wyu1_w, wyu1_b, wy1, wu1_w, wu1_b,
        wzu2_w, wzu2_b, wz2, wyu2_w, wyu2_b, wy2, out);
}

// Round 7
// 150.483 us; speedup vs baseline: 1.0307x; 1.0137x over previous
//
#include <hip/hip_runtime.h>
#include <math.h>

#define NB 256        // batch = grid
#define N 128         // DIMX = DIMY = DIMH
#define NTHREADS 1024 // 16 waves; thread = (k<<3)|h, k=0..127 row, h=0..7 slice
#define MAX_IT 500
// 128-vectors in LDS: 8 slices of 16 floats, slice stride 20 words -> the 8
// h-slice base banks {0,20,8,28,16,4,24,12} are distinct: conflict-free b128
// broadcast reads within a wave.
#define SL8 20
#define SLOT8(c) (((c) >> 4) * SL8 + ((c) & 15))
#define VLEN (7 * SL8 + 16)
#define WZP 132       // WzT row pitch (words); 4-way conflict (1.58x) accepted

// Heavy-ball on spectrum [mu=0.5, L=1.45]: uniform |root| ~= 0.26/iter.
#define HBALPHA 1.10f
#define HBBETA  0.068f
// Exit: |r_k| <= 1e-3 for all k => ||r||2 <= 1.13e-2 => ||y1-y1*||2 <= 2.3e-2
// (mu=0.5) => per-sample output err <= 2.3e-2/sqrt(128) ~= 2e-3 << 1.79e-2.
#define TPC 1.0e-3f

// 8-lane reduction: lanes 8q..8q+7 hold the 8 h-slices of one k.
// xor1/xor2 via DPP quad_perm (in-quad), xor4 via shfl (cross-quad).
template <int CTRL>
__device__ __forceinline__ float dpp_addx(float v) {
    int sw = __builtin_amdgcn_update_dpp(0, __float_as_int(v), CTRL, 0xF, 0xF, true);
    return v + __int_as_float(sw);
}
__device__ __forceinline__ float sum8(float p) {
    p = dpp_addx<0xB1>(p);     // quad_perm [1,0,3,2]
    p = dpp_addx<0x4E>(p);     // quad_perm [2,3,0,1]
    p += __shfl_xor(p, 4);
    return p;
}
__device__ __forceinline__ float wave_sum(float p) {  // epilogue only
    p += __shfl_xor(p, 1);  p += __shfl_xor(p, 2);
    p += __shfl_xor(p, 4);  p += __shfl_xor(p, 8);
    p += __shfl_xor(p, 16); p += __shfl_xor(p, 32);
    return p;
}
__device__ __forceinline__ float softplus_f(float s) {
    float e = __expf(-fabsf(s));
    return fmaxf(s, 0.f) + __logf(1.f + e);
}
__device__ __forceinline__ float sigmoid_f(float s) {
    float e = __expf(-fabsf(s));
    float r = 1.f / (1.f + e);
    return s >= 0.f ? r : 1.f - r;
}

// row matvec: W row k (global) dot 128-vector V (LDS slice layout)
__device__ __forceinline__ float mv16(const float* __restrict__ W,
                                      const float* __restrict__ V,
                                      int k, int h) {
    const float4* wr = (const float4*)(W + k * N + h * 16);
    const float4* vr = (const float4*)(V + h * SL8);
    float q0 = 0.f, q1 = 0.f, q2 = 0.f, q3 = 0.f;
#pragma unroll
    for (int i = 0; i < 4; ++i) {
        float4 w = wr[i], v = vr[i];
        q0 = fmaf(w.x, v.x, q0); q1 = fmaf(w.y, v.y, q1);
        q2 = fmaf(w.z, v.z, q2); q3 = fmaf(w.w, v.w, q3);
    }
    return sum8((q0 + q1) + (q2 + q3));
}

__global__ __launch_bounds__(NTHREADS, 4)   // 4 waves/EU -> <=128 VGPR/thread
void picnn_solve(const float* __restrict__ x, const float* __restrict__ y,
                 const float* __restrict__ wuu0_w, const float* __restrict__ wuu0_b,
                 const float* __restrict__ wyu0_w, const float* __restrict__ wyu0_b,
                 const float* __restrict__ wy0,
                 const float* __restrict__ wu0_w, const float* __restrict__ wu0_b,
                 const float* __restrict__ wuu1_w, const float* __restrict__ wuu1_b,
                 const float* __restrict__ wzu1_w, const float* __restrict__ wzu1_b,
                 const float* __restrict__ wz1,
                 const float* __restrict__ wyu1_w, const float* __restrict__ wyu1_b,
                 const float* __restrict__ wy1,
                 const float* __restrict__ wu1_w, const float* __restrict__ wu1_b,
                 const float* __restrict__ wzu2_w, const float* __restrict__ wzu2_b,
                 const float* __restrict__ wz2,
                 const float* __restrict__ wyu2_w, const float* __restrict__ wyu2_b,
                 const float* __restrict__ wy2,
                 float* __restrict__ out)
{
    const int b = blockIdx.x;
    const int t = threadIdx.x;
    const int k = t >> 3;   // output row 0..127
    const int h = t & 7;    // 16-element slice 0..7
    const int wave = t >> 6;
    const int lane = t & 63;

    __shared__ __align__(16) float WzT[N * WZP];  // Wz^T * diag(zu), 67.6 KB
    __shared__ __align__(16) float xv[VLEN];
    __shared__ __align__(16) float u0v[VLEN];
    __shared__ __align__(16) float u1v[VLEN];
    __shared__ __align__(16) float a0s[VLEN];
    __shared__ __align__(16) float a1s[VLEN];
    __shared__ __align__(16) float zuv[VLEN];
    __shared__ __align__(16) float vs[VLEN];
    __shared__ __align__(16) float t1s[VLEN];
    __shared__ __align__(16) float d2s[VLEN];
    __shared__ __align__(16) float d1s[VLEN];
    __shared__ float rp[16];
    __shared__ int cflag[2];

    if (t < N) xv[SLOT8(t)] = x[b * N + t];
    if (t < 2) cflag[t] = 0;
    __syncthreads();

    // ---- per-sample iteration-invariant precompute ----
    float u0k = softplus_f(mv16(wuu0_w, xv, k, h) + wuu0_b[k]);
    float a0  = mv16(wyu0_w, xv, k, h) + wyu0_b[k];
    float c0  = mv16(wu0_w,  xv, k, h) + wu0_b[k];
    if (h == 0) { u0v[SLOT8(k)] = u0k; a0s[SLOT8(k)] = a0; }
    __syncthreads();

    float u1k = softplus_f(mv16(wuu1_w, u0v, k, h) + wuu1_b[k]);
    float zu  = softplus_f(mv16(wzu1_w, u0v, k, h) + wzu1_b[k]);
    float a1  = mv16(wyu1_w, u0v, k, h) + wyu1_b[k];
    float c1  = mv16(wu1_w,  u0v, k, h) + wu1_b[k];
    if (h == 0) { u1v[SLOT8(k)] = u1k; a1s[SLOT8(k)] = a1; zuv[SLOT8(k)] = zu; }
    __syncthreads();

    float a2 = mv16(wyu2_w, u1v, k, h) + wyu2_b[k];
    float e2 = a2 * wy2[k];
    float dp;
    {
        const float4* wr = (const float4*)(wzu2_w + h * 16);
        const float4* vr = (const float4*)(u1v + h * SL8);
        float q0 = 0.f, q1 = 0.f, q2 = 0.f, q3 = 0.f;
#pragma unroll
        for (int i = 0; i < 4; ++i) {
            float4 w = wr[i], v = vr[i];
            q0 = fmaf(w.x, v.x, q0); q1 = fmaf(w.y, v.y, q1);
            q2 = fmaf(w.z, v.z, q2); q3 = fmaf(w.w, v.w, q3);
        }
        float zu2 = softplus_f(sum8((q0 + q1) + (q2 + q3)) + wzu2_b[0]);
        dp = zu2 * fmaxf(wz2[k], 0.f);
    }

    // ---- weights (AFTER precompute; hoisting spills -- R3/R6 lesson) ----
    // Registers (16 floats each): A0=wy0*diag(a0) rows, B=wy1*diag(a1) rows,
    // WzR=clip(wz1)*diag(zu) rows, A0^T cols (*a0_k), B^T cols (*a1_k).
    // LDS: WzT[k][j] = clip(wz1)[j][k]*zu_k (fold kills zu from the loop).
    float4 wf0[4], wf2[4], wf1z[4];   // rows, slice h
    float4 wb0[4], wb2[4];            // columns, row-slice h
    {
        const float4* r0  = (const float4*)(wy0 + k * N + h * 16);
        const float4* r1  = (const float4*)(wz1 + k * N + h * 16);
        const float4* r2  = (const float4*)(wy1 + k * N + h * 16);
        const float4* aa0 = (const float4*)(a0s + h * SL8);
        const float4* aa1 = (const float4*)(a1s + h * SL8);
        const float4* zz  = (const float4*)(zuv + h * SL8);
#pragma unroll
        for (int i = 0; i < 4; ++i) {
            float4 w = r0[i], s = aa0[i];
            w.x *= s.x; w.y *= s.y; w.z *= s.z; w.w *= s.w;
            wf0[i] = w;
            w = r2[i]; s = aa1[i];
            w.x *= s.x; w.y *= s.y; w.z *= s.z; w.w *= s.w;
            wf2[i] = w;
            w = r1[i]; s = zz[i];
            w.x = fmaxf(w.x, 0.f) * s.x; w.y = fmaxf(w.y, 0.f) * s.y;
            w.z = fmaxf(w.z, 0.f) * s.z; w.w = fmaxf(w.w, 0.f) * s.w;
            wf1z[i] = w;
        }
        // column gathers (16 scalars each) + WzT build (contiguous b128 LDS)
        float4* wrow = (float4*)(WzT + k * WZP + h * 16);
#pragma unroll
        for (int i = 0; i < 4; ++i) {
            int j = h * 16 + 4 * i;
            wb0[i].x = wy0[(j + 0) * N + k] * a0;
            wb0[i].y = wy0[(j + 1) * N + k] * a0;
            wb0[i].z = wy0[(j + 2) * N + k] * a0;
            wb0[i].w = wy0[(j + 3) * N + k] * a0;
            wb2[i].x = wy1[(j + 0) * N + k] * a1;
            wb2[i].y = wy1[(j + 1) * N + k] * a1;
            wb2[i].z = wy1[(j + 2) * N + k] * a1;
            wb2[i].w = wy1[(j + 3) * N + k] * a1;
            float4 wz;
            wz.x = fmaxf(wz1[(j + 0) * N + k], 0.f) * zu;
            wz.y = fmaxf(wz1[(j + 1) * N + k], 0.f) * zu;
            wz.z = fmaxf(wz1[(j + 2) * N + k], 0.f) * zu;
            wz.w = fmaxf(wz1[(j + 3) * N + k], 0.f) * zu;
            wrow[i] = wz;
        }
    }

    const float yk = y[b * N + k];
    // init zeroing the linear residual part: g ~ 0.5*y1 + e2 -> y1_0 = 2(y-e2)
    float y1v = 2.f * (yk - e2);
    float y1p = y1v;
    if (h == 0) vs[SLOT8(k)] = y1v;
    __syncthreads();

    float gcB = 0.f, sig1 = 0.f;
    for (int it = 1; it <= MAX_IT; ++it) {
        // S1: s1 = A0rows.v + c0 ; s2a = Brows.v (one vector pass)
        const float4* vr = (const float4*)(vs + h * SL8);
        float p0 = 0.f, p1 = 0.f, p2 = 0.f, p3 = 0.f;
        float q0 = 0.f, q1 = 0.f, q2 = 0.f, q3 = 0.f;
#pragma unroll
        for (int i = 0; i < 4; ++i) {
            float4 v = vr[i];
            p0 = fmaf(wf0[i].x, v.x, p0); p1 = fmaf(wf0[i].y, v.y, p1);
            p2 = fmaf(wf0[i].z, v.z, p2); p3 = fmaf(wf0[i].w, v.w, p3);
            q0 = fmaf(wf2[i].x, v.x, q0); q1 = fmaf(wf2[i].y, v.y, q1);
            q2 = fmaf(wf2[i].z, v.z, q2); q3 = fmaf(wf2[i].w, v.w, q3);
        }
        float s1  = sum8((p0 + p1) + (p2 + p3)) + c0;
        float s2a = sum8((q0 + q1) + (q2 + q3));
        float e1 = __expf(-fabsf(s1));
        float z1 = fmaxf(s1, 0.f) + __logf(1.f + e1);
        float rr1 = 1.f / (1.f + e1);
        sig1 = (s1 >= 0.f) ? rr1 : 1.f - rr1;
        if (h == 0) t1s[SLOT8(k)] = z1;          // zu folded into WzR/WzT
        __syncthreads();

        // S2: s2 = WzRrows.z1 + s2a + c1 ; d2 = dp*sigma(s2)
        const float4* t1r = (const float4*)(t1s + h * SL8);
        p0 = p1 = p2 = p3 = 0.f;
#pragma unroll
        for (int i = 0; i < 4; ++i) {
            float4 v1 = t1r[i];
            p0 = fmaf(wf1z[i].x, v1.x, p0); p1 = fmaf(wf1z[i].y, v1.y, p1);
            p2 = fmaf(wf1z[i].z, v1.z, p2); p3 = fmaf(wf1z[i].w, v1.w, p3);
        }
        float s2 = sum8((p0 + p1) + (p2 + p3)) + s2a + c1;
        float d2 = dp * sigmoid_f(s2);
        if (h == 0) d2s[SLOT8(k)] = d2;
        __syncthreads();

        // S3: wv = WzT(row k).d2 ; gcB = Bcols.d2 ; d1 = wv*sig1
        if (t == 0) cflag[(it + 1) & 1] = 0;
        const float4* d2r = (const float4*)(d2s + h * SL8);
        const float4* wzr = (const float4*)(WzT + k * WZP + h * 16);
        p0 = p1 = p2 = p3 = 0.f; q0 = q1 = q2 = q3 = 0.f;
#pragma unroll
        for (int i = 0; i < 4; ++i) {
            float4 d = d2r[i], w = wzr[i];
            p0 = fmaf(w.x, d.x, p0); p1 = fmaf(w.y, d.y, p1);
            p2 = fmaf(w.z, d.z, p2); p3 = fmaf(w.w, d.w, p3);
            q0 = fmaf(wb2[i].x, d.x, q0); q1 = fmaf(wb2[i].y, d.y, q1);
            q2 = fmaf(wb2[i].z, d.z, q2); q3 = fmaf(wb2[i].w, d.w, q3);
        }
        float wv = sum8((p0 + p1) + (p2 + p3));
        gcB = sum8((q0 + q1) + (q2 + q3));
        float d1 = wv * sig1;
        if (h == 0) d1s[SLOT8(k)] = d1;
        __syncthreads();

        // S4: gbA = A0cols.d1 ; g ; heavy-ball update; exit flag
        const float4* d1r = (const float4*)(d1s + h * SL8);
        p0 = p1 = p2 = p3 = 0.f;
#pragma unroll
        for (int i = 0; i < 4; ++i) {
            float4 d = d1r[i];
            p0 = fmaf(wb0[i].x, d.x, p0); p1 = fmaf(wb0[i].y, d.y, p1);
            p2 = fmaf(wb0[i].z, d.z, p2); p3 = fmaf(wb0[i].w, d.w, p3);
        }
        float gbA = sum8((p0 + p1) + (p2 + p3));
        float g = fmaf(0.5f, y1v, e2) + gcB + gbA;
        float rres = yk - g;
        float y1n = y1v + HBALPHA * rres + HBBETA * (y1v - y1p);
        y1p = y1v; y1v = y1n;
        if (h == 0) vs[SLOT8(k)] = y1v;
        if (__ballot(fabsf(rres) > TPC)) {
            if (lane == 0) cflag[it & 1] = 1;
        }
        __syncthreads();
        if (!cflag[it & 1]) break;               // uniform post-barrier read
    }

    // out[b] = mean_k(y1 + y); each k duplicated 8x -> /1024
    float v = wave_sum(y1v + yk);
    if (lane == 0) rp[wave] = v;
    __syncthreads();
    if (t == 0) {
        float s = 0.f;
#pragma unroll
        for (int i = 0; i < 16; ++i) s += rp[i];
        out[b] = s * (1.f / 1024.f);
    }
}

extern "C" void kernel_launch(void* const* d_in, const int* in_sizes, int n_in,
                              void* d_out, int out_size, void* d_ws, size_t ws_size,
                              hipStream_t stream) {
    const float* x      = (const float*)d_in[0];
    const float* y      = (const float*)d_in[1];
    const float* wuu0_w = (const float*)d_in[2];
    const float* wuu0_b = (const float*)d_in[3];
    const float* wyu0_w = (const float*)d_in[4];
    const float* wyu0_b = (const float*)d_in[5];
    const float* wy0    = (const float*)d_in[6];
    const float* wu0_w  = (const float*)d_in[7];
    const float* wu0_b  = (const float*)d_in[8];
    const float* wuu1_w = (const float*)d_in[9];
    const float* wuu1_b = (const float*)d_in[10];
    const float* wzu1_w = (const float*)d_in[11];
    const float* wzu1_b = (const float*)d_in[12];
    const float* wz1    = (const float*)d_in[13];
    const float* wyu1_w = (const float*)d_in[14];
    const float* wyu1_b = (const float*)d_in[15];
    const float* wy1    = (const float*)d_in[16];
    const float* wu1_w  = (const float*)d_in[17];
    const float* wu1_b  = (const float*)d_in[18];
    const float* wzu2_w = (const float*)d_in[19];
    const float* wzu2_b = (const float*)d_in[20];
    const float* wz2    = (const float*)d_in[21];
    const float* wyu2_w = (const float*)d_in[22];
    const float* wyu2_b = (const float*)d_in[23];
    const float* wy2    = (const float*)d_in[24];
    // d_in[25]/[26] (wu2_w, wu2_b) shift the value, not the gradient -> unused
    float* out = (float*)d_out;

    picnn_solve<<<dim3(NB), dim3(NTHREADS), 0, stream>>>(
        x, y, wuu0_w, wuu0_b, wyu0_w, wyu0_b, wy0, wu0_w, wu0_b,
        wuu1_w, wuu1_b, wzu1_w, wzu1_b, wz1, wyu1_w, wyu1_b, wy1, wu1_w, wu1_b,
        wzu2_w, wzu2_b, wz2, wyu2_w, wyu2_b, wy2, out);
}